// Round 9
// baseline (424.701 us; speedup 1.0000x reference)
//
#include <hip/hip_runtime.h>
#include <hip/hip_bf16.h>
#include <cstdint>

typedef __bf16 bf16;
typedef __attribute__((ext_vector_type(8))) __bf16 bf16x8;
typedef __attribute__((ext_vector_type(4))) __bf16 bf16x4;
typedef __attribute__((ext_vector_type(2))) __bf16 bf16x2;
typedef __attribute__((ext_vector_type(4))) float f32x4;

constexpr int DIM = 384;
constexpr int HEAD_DIM = 48;
constexpr int ADLA_N = 343;
constexpr int NTOK = 2744;        // 14^3
constexpr int BATCH = 8;
constexpr int MTOT = BATCH * NTOK; // 21952
constexpr float SCALE = 0.14433756729740643f; // 48^-0.5
constexpr float LOG2E = 1.4426950408889634f;
constexpr float SCALE2 = 0.20823512f;         // SCALE * log2(e); biases pre-scaled
constexpr int B1W = 2816;          // bias1 padded width (44*64)
constexpr int B2W = 384;           // bias2 padded width (6*64)
constexpr int ADV_W = 352;         // adla_v^T padded cols
constexpr int SEG = 6;             // attn1 column-split segments (8x64 chunks each)

// ---------------- weight transpose (f32 in -> bf16 out) -------------------------
__global__ void transpose_weights(const float* __restrict__ Wq,
                                  const float* __restrict__ Wkv,
                                  const float* __restrict__ Wproj,
                                  bf16* __restrict__ WTall,
                                  bf16* __restrict__ WprojT) {
  int idx = blockIdx.x * 256 + threadIdx.x;
  const int total1 = 1152 * 384;
  if (idx < total1) {
    int j = idx / 384, k = idx % 384;
    WTall[idx] = (bf16)((j < 384) ? Wq[k * 384 + j] : Wkv[k * 768 + (j - 384)]);
  } else {
    int i2 = idx - total1;
    if (i2 < 384 * 384) {
      int j = i2 / 384, k = i2 % 384;
      WprojT[i2] = (bf16)Wproj[k * 384 + j];
    }
  }
}

// ---------------- trilinear interp helpers (out 14 from in 7) ------------------
__device__ __forceinline__ void lin_w(int i, int& i0, int& i1, float& w) {
  float f = 0.5f * (float)i - 0.25f;
  f = fminf(fmaxf(f, 0.0f), 6.0f);
  i0 = (int)f;
  w = f - (float)i0;
  i1 = (i0 + 1 < 7) ? i0 + 1 : 6;
}

__device__ __forceinline__ float interp3(const float* __restrict__ p, int x, int y, int z) {
  int x0, x1, y0, y1, z0, z1; float wx, wy, wz;
  lin_w(x, x0, x1, wx); lin_w(y, y0, y1, wy); lin_w(z, z0, z1, wz);
  float c000 = p[x0*49 + y0*7 + z0], c001 = p[x0*49 + y0*7 + z1];
  float c010 = p[x0*49 + y1*7 + z0], c011 = p[x0*49 + y1*7 + z1];
  float c100 = p[x1*49 + y0*7 + z0], c101 = p[x1*49 + y0*7 + z1];
  float c110 = p[x1*49 + y1*7 + z0], c111 = p[x1*49 + y1*7 + z1];
  float c00 = c000 + wz * (c001 - c000), c01 = c010 + wz * (c011 - c010);
  float c10 = c100 + wz * (c101 - c100), c11 = c110 + wz * (c111 - c110);
  float c0 = c00 + wy * (c01 - c00), c1 = c10 + wy * (c11 - c10);
  return c0 + wx * (c1 - c0);
}

// ---------------- bias1[h][a][B1W] = (interp(an)+ah+aw+ad) * log2e --------------
__global__ void bias1_kernel(const float* __restrict__ an, const float* __restrict__ ah,
                             const float* __restrict__ aw, const float* __restrict__ ad,
                             bf16* __restrict__ out) {
  int h = blockIdx.x / ADLA_N, a = blockIdx.x % ADLA_N;
  const float* anp = an + ((size_t)h * ADLA_N + a) * 343;
  const float* ahp = ah + ((size_t)h * ADLA_N + a) * 14;
  const float* awp = aw + ((size_t)h * ADLA_N + a) * 14;
  const float* adp = ad + ((size_t)h * ADLA_N + a) * 14;
  bf16* op = out + ((size_t)h * ADLA_N + a) * B1W;
  for (int n = threadIdx.x; n < B1W; n += 256) {
    if (n < NTOK) {
      int x = n / 196, y = (n / 14) % 14, z = n % 14;
      float v = interp3(anp, x, y, z) + ahp[x] + awp[y] + adp[z];
      op[n] = (bf16)(v * LOG2E);
    } else {
      op[n] = (bf16)0.f;   // finite zero pad (read by attn1, masked)
    }
  }
}

// ---------------- bias2[h][n][B2W] tiled: lanes-along-n gathers, LDS transpose --
// Pre-scaled by log2(e) (see bias1).
__global__ __launch_bounds__(256)
void bias2_kernel(const float* __restrict__ na, const float* __restrict__ ha,
                  const float* __restrict__ wa, const float* __restrict__ da,
                  bf16* __restrict__ out) {
  __shared__ bf16 t[64 * 66];
  const int tid = threadIdx.x;
  const int wv = tid >> 6, lane = tid & 63;
  const int n0 = blockIdx.x * 64, a0 = blockIdx.y * 64;
  const int h = blockIdx.z;
  const int nc = min(n0 + lane, NTOK - 1);
  const int x = nc / 196, y = (nc / 14) % 14, z = nc % 14;
  int x0, x1, y0, y1, z0, z1; float wx, wy, wz;
  lin_w(x, x0, x1, wx); lin_w(y, y0, y1, wy); lin_w(z, z0, z1, wz);
  const int o[8] = { x0*49 + y0*7 + z0, x0*49 + y0*7 + z1,
                     x0*49 + y1*7 + z0, x0*49 + y1*7 + z1,
                     x1*49 + y0*7 + z0, x1*49 + y0*7 + z1,
                     x1*49 + y1*7 + z0, x1*49 + y1*7 + z1 };
  const float wgt[8] = { (1.f-wx)*(1.f-wy)*(1.f-wz), (1.f-wx)*(1.f-wy)*wz,
                         (1.f-wx)*wy*(1.f-wz),       (1.f-wx)*wy*wz,
                         wx*(1.f-wy)*(1.f-wz),       wx*(1.f-wy)*wz,
                         wx*wy*(1.f-wz),             wx*wy*wz };
#pragma unroll
  for (int j = 0; j < 16; j++) {
    const int al = wv * 16 + j;
    const int a = a0 + al;
    float s = 0.f;
    if (a < ADLA_N) {
      const float* p = na + ((size_t)h * ADLA_N + a) * 343;
#pragma unroll
      for (int k = 0; k < 8; k++) s += p[o[k]] * wgt[k];
      s += ha[((size_t)h * 14 + x) * ADLA_N + a]
         + wa[((size_t)h * 14 + y) * ADLA_N + a]
         + da[((size_t)h * 14 + z) * ADLA_N + a];
    }
    t[lane * 66 + al] = (bf16)(s * LOG2E);
  }
  __syncthreads();
#pragma unroll
  for (int j = 0; j < 16; j++) {
    const int nr = wv * 16 + j;
    if (n0 + nr < NTOK)
      out[((size_t)h * NTOK + n0 + nr) * B2W + a0 + lane] = t[nr * 66 + lane];
  }
}

// ---------------- 128x128 MFMA GEMM, K=384, B^T (bf16) --------------------------
// XCD-panel swizzle (T1): 1-D grid; id&7 = XCD, each XCD owns 22 contiguous
// m-panels with n fastest -> the NB blocks sharing an A-panel run consecutively
// on the SAME XCD, so the panel (196KB f32 / 98KB bf16) stays in its 4MB L2.
// Old (172,9) grid re-read all of A once per n-panel from L3 (~300MB/dispatch).
template <int MODE, typename AT, typename OT>
__global__ __launch_bounds__(256)
void gemm128(const AT* __restrict__ A, const bf16* __restrict__ BT, int M,
             OT* __restrict__ O0, bf16* __restrict__ O1, bf16* __restrict__ O2,
             const float* __restrict__ bias) {
  constexpr int NB = (MODE == 0) ? 9 : 3;   // n-panels
  const int id = blockIdx.x;
  const int xcd = id & 7;
  const int t0 = id >> 3;                   // 0 .. 22*NB-1
  const int mi = xcd * 22 + t0 / NB;
  const int ni = t0 % NB;
  if (mi >= 172) return;                    // uniform early-exit (pad blocks)
  const int m0 = mi * 128, n0 = ni * 128;

  __shared__ __align__(16) bf16 As[128 * 40];
  __shared__ __align__(16) bf16 Bs[128 * 40];
  const int tid = threadIdx.x;
  const int wv = tid >> 6, lane = tid & 63;
  const int wr = wv >> 1, wc = wv & 1;
  f32x4 zero4 = {0.f, 0.f, 0.f, 0.f};
  f32x4 acc[4][4];
#pragma unroll
  for (int i = 0; i < 4; i++)
#pragma unroll
    for (int j = 0; j < 4; j++) acc[i][j] = zero4;

  for (int k0 = 0; k0 < 384; k0 += 32) {
    __syncthreads();
#pragma unroll
    for (int i = 0; i < 2; i++) {
      int flat = i * 256 + tid;
      int row = flat >> 2, cg = flat & 3;
      int gr = m0 + row; if (gr >= M) gr = M - 1;
      bf16x8 av;
      if constexpr (sizeof(AT) == 4) {
        const float4* s4 = (const float4*)(A + (size_t)gr * 384 + k0 + cg * 8);
        float4 a = s4[0], b = s4[1];
        av[0]=(bf16)a.x; av[1]=(bf16)a.y; av[2]=(bf16)a.z; av[3]=(bf16)a.w;
        av[4]=(bf16)b.x; av[5]=(bf16)b.y; av[6]=(bf16)b.z; av[7]=(bf16)b.w;
      } else {
        av = *(const bf16x8*)(A + (size_t)gr * 384 + k0 + cg * 8);
      }
      *(bf16x8*)(As + row * 40 + cg * 8) = av;
      int nr = n0 + row;
      *(bf16x8*)(Bs + row * 40 + cg * 8) = *(const bf16x8*)(BT + (size_t)nr * 384 + k0 + cg * 8);
    }
    __syncthreads();
    bf16x8 af[4], bfr[4];
#pragma unroll
    for (int t = 0; t < 4; t++) {
      af[t]  = *(const bf16x8*)(As + (wr * 64 + t * 16 + (lane & 15)) * 40 + (lane >> 4) * 8);
      bfr[t] = *(const bf16x8*)(Bs + (wc * 64 + t * 16 + (lane & 15)) * 40 + (lane >> 4) * 8);
    }
    __builtin_amdgcn_s_setprio(1);
#pragma unroll
    for (int rt = 0; rt < 4; rt++)
#pragma unroll
      for (int ct = 0; ct < 4; ct++)
        acc[rt][ct] = __builtin_amdgcn_mfma_f32_16x16x32_bf16(af[rt], bfr[ct], acc[rt][ct], 0, 0, 0);
    __builtin_amdgcn_s_setprio(0);
  }
  const int quad = lane >> 4, colL = lane & 15;
#pragma unroll
  for (int rt = 0; rt < 4; rt++) {
#pragma unroll
    for (int ct = 0; ct < 4; ct++) {
      int gcol = n0 + wc * 64 + ct * 16 + colL;
#pragma unroll
      for (int r = 0; r < 4; r++) {
        int grow = m0 + wr * 64 + rt * 16 + quad * 4 + r;
        if (grow < M) {
          float v = acc[rt][ct][r];
          if (MODE == 1) {
            v += bias[gcol];
            O0[(size_t)grow * 384 + gcol] = (OT)v;   // OT=float for final output
          } else {
            bf16* dst; int c;
            if (gcol < 384)      { dst = (bf16*)O0; c = gcol; }
            else if (gcol < 768) { dst = O1; c = gcol - 384; }
            else                 { dst = O2; c = gcol - 768; }
            dst[(size_t)grow * 384 + c] = (bf16)v;
          }
        }
      }
    }
  }
}

// ---------------- v -> vT  ([b][n][c] -> [b][c][n]) -----------------------------
__global__ void transpose_v(const bf16* __restrict__ v, bf16* __restrict__ vT) {
  __shared__ bf16 t[64][65];
  int n0 = blockIdx.x * 64, c0 = blockIdx.y * 64, b = blockIdx.z;
  int tid = threadIdx.x;
  int cl = tid & 63, rs = tid >> 6;
  for (int j = 0; j < 16; j++) {
    int r = rs * 16 + j;
    int n = n0 + r;
    if (n < NTOK) t[cl][r] = v[((size_t)b * NTOK + n) * DIM + c0 + cl];
  }
  __syncthreads();
  int nl = tid & 63, cs = tid >> 6;
  int n = n0 + nl;
  if (n < NTOK)
    for (int j = 0; j < 16; j++) {
      int cc = cs * 16 + j;
      vT[((size_t)b * DIM + c0 + cc) * NTOK + n] = t[cc][nl];
    }
}

// ---------------- 2x2x2 mean-pool of q -> adla [b][343][384] --------------------
__global__ void pool_kernel(const bf16* __restrict__ q, bf16* __restrict__ adla) {
  int idx = blockIdx.x * 256 + threadIdx.x;
  if (idx >= BATCH * ADLA_N * DIM) return;
  int c = idx % DIM;
  int a = (idx / DIM) % ADLA_N;
  int b = idx / (DIM * ADLA_N);
  int a0 = a / 49, a1 = (a / 7) % 7, a2 = a % 7;
  float s = 0.f;
#pragma unroll
  for (int i = 0; i < 2; i++)
#pragma unroll
    for (int j = 0; j < 2; j++)
#pragma unroll
      for (int k = 0; k < 2; k++) {
        int n = (a0 * 2 + i) * 196 + (a1 * 2 + j) * 14 + (a2 * 2 + k);
        s += (float)q[((size_t)b * NTOK + n) * DIM + c];
      }
  adla[idx] = (bf16)(s * 0.125f);
}

// ---------------- unified no-max streaming attention (bf16 internals) -----------
// S^T-form + reg A-fragments + async-stage split + XCD swizzle + 1-barrier dbuf
// + exp2 softmax (biases pre-scaled by log2e). NEW: s_setprio(1) around the
// MFMA clusters (T5: blocks are phase-independent -> CU scheduler favors the
// wave feeding the matrix pipe).
template <int MODE>
__global__ __launch_bounds__(256, 4)
void attn_kernel(const bf16* __restrict__ Amat, const bf16* __restrict__ Kmat,
                 const bf16* __restrict__ Vt, const bf16* __restrict__ Bias,
                 bf16* __restrict__ Out, float* __restrict__ OutP,
                 float* __restrict__ RsP,
                 int AR, int NC, int biasW,
                 size_t vtB, size_t vtH, int vtS) {
  __shared__ __align__(16) bf16 kT[2][64 * 64];
  __shared__ __align__(16) bf16 vTs[2][48 * 64];
  __shared__ __align__(16) bf16 pT[64 * 64];
  const int tid = threadIdx.x;
  const int wv = tid >> 6, lane = tid & 63;

  // ---- XCD-aware swizzled block decomposition (1-D grid) ----
  int h, bI, rblk, seg;
  {
    const int id = blockIdx.x;
    h = id & 7;
    int t = id >> 3;
    if (MODE == 0) { rblk = t % 6; t /= 6; bI = t & 7; seg = t >> 3; }
    else           { bI = t & 7; rblk = t >> 3; seg = 0; }
  }
  const int bh = bI * 8 + h;
  const int r0 = rblk * 64;
  const int quad = lane >> 4, colL = lane & 15;
  const int rowL = wv * 16 + colL;                 // this thread's S-row (fixed)

  // ---- A fragments straight to registers (row clamped; k>=48 zero) ----
  int ar = r0 + rowL; if (ar >= AR) ar = AR - 1;
  const bf16* aRow = Amat + ((size_t)bI * AR + ar) * DIM + h * HEAD_DIM;
  bf16x8 af0 = *(const bf16x8*)(aRow + quad * 8);          // k = quad*8 .. +7 (<48)
  bf16x8 af1;
#pragma unroll
  for (int e = 0; e < 8; e++) af1[e] = (bf16)0.f;
  if (quad < 2) af1 = *(const bf16x8*)(aRow + 32 + quad * 8); // k = 32..47; else 0

  f32x4 zero4 = {0.f, 0.f, 0.f, 0.f};
  f32x4 acc[3] = {zero4, zero4, zero4};
  float rowsum = 0.f;
  const int nCh = (NC + 63) >> 6;                  // 64-col chunks
  const int ch0 = (MODE == 0) ? seg * 8 : 0;
  const int ch1 = (MODE == 0) ? min(nCh, ch0 + 8) : nCh;
  int br = r0 + rowL; if (br >= AR) br = AR - 1;   // clamp (stay inside bias[h])
  const bf16* biasRow = Bias + ((size_t)h * AR + br) * biasW + quad * 4;

  // ---- staging coords (wave-invariant forms) ----
  bf16x8 kreg[2], vreg[2];
  auto load_tile = [&](int ch) {
    const int c0 = ch << 6;
#pragma unroll
    for (int i = 0; i < 2; i++) {
      int flat = i * 256 + tid;
      int row = flat >> 3, cg = flat & 7;
      int kg = (cg < 6) ? cg : 0;                  // cols 48..63 finite dup (A zero there)
      int gr = c0 + row; if (gr >= NC) gr = NC - 1;
      kreg[i] = *(const bf16x8*)(Kmat + ((size_t)bI * NC + gr) * DIM + h * HEAD_DIM + kg * 8);
    }
#pragma unroll
    for (int i = 0; i < 2; i++) {
      int flat = i * 256 + tid;
      int d = flat >> 3; if (d > 47) d = 47;
      int cg = flat & 7;
      int cc = c0 + cg * 8; if (cc > vtS - 8) cc = vtS - 8;  // column clamp
      vreg[i] = *(const bf16x8*)(Vt + (size_t)bI * vtB + (size_t)h * vtH + (size_t)d * vtS + cc);
    }
  };
  auto write_tile = [&](int buf) {
    bf16* kd = kT[buf];
    bf16* vd = vTs[buf];
#pragma unroll
    for (int i = 0; i < 2; i++) {
      int flat = i * 256 + tid;
      int row = flat >> 3, cg = flat & 7;
      *(bf16x8*)(kd + row * 64 + ((cg ^ (row & 7)) << 3)) = kreg[i];
    }
#pragma unroll
    for (int i = 0; i < 2; i++) {
      int flat = i * 256 + tid;
      int d = flat >> 3; if (d > 47) d = 47;
      int cg = flat & 7;
      *(bf16x8*)(vd + d * 64 + ((cg ^ (d & 7)) << 3)) = vreg[i];
    }
  };

  // prologue: stage first chunk into buf0
  load_tile(ch0);
  write_tile(0);
  __syncthreads();
  int cur = 0;

  for (int ch = ch0; ch < ch1; ch++) {
    const int c0 = ch << 6;
    const bool hasNext = (ch + 1 < ch1);
    // issue NEXT chunk's global loads now; they complete under S+exp+PV
    if (hasNext) load_tile(ch + 1);

    // bias vector loads for this chunk (hide under S MFMAs)
    bf16x4 bv[4];
#pragma unroll
    for (int ct = 0; ct < 4; ct++)
      bv[ct] = *(const bf16x4*)(biasRow + c0 + ct * 16);

    const bf16* kc = kT[cur];
    const bf16* vc = vTs[cur];

    // S^T phase: sacc[ct] tile = [c rows ct*16..+16][r cols wv*16..+16]
    f32x4 sacc[4];
#pragma unroll
    for (int ct = 0; ct < 4; ct++) sacc[ct] = zero4;
    __builtin_amdgcn_s_setprio(1);
#pragma unroll
    for (int ct = 0; ct < 4; ct++) {
      int krow = ct * 16 + colL;
      bf16x8 b0 = *(const bf16x8*)(kc + krow * 64 + ((quad ^ (krow & 7)) << 3));
      bf16x8 b1 = *(const bf16x8*)(kc + krow * 64 + (((4 | quad) ^ (krow & 7)) << 3));
      sacc[ct] = __builtin_amdgcn_mfma_f32_16x16x32_bf16(b0, af0, sacc[ct], 0, 0, 0);
      sacc[ct] = __builtin_amdgcn_mfma_f32_16x16x32_bf16(b1, af1, sacc[ct], 0, 0, 0);
    }
    __builtin_amdgcn_s_setprio(0);
    // bias + exp2 -> packed bf16x4 P writes into swizzled pT (own row; no barrier)
#pragma unroll
    for (int ct = 0; ct < 4; ct++) {
      int cbase = c0 + ct * 16 + quad * 4;     // global col of elem 0
      bf16x4 pw;
#pragma unroll
      for (int j = 0; j < 4; j++) {
        float s = fmaf(sacc[ct][j], SCALE2, (float)bv[ct][j]);
        float p = ((cbase + j) < NC) ? __builtin_amdgcn_exp2f(s) : 0.f;
        rowsum += p;
        pw[j] = (bf16)p;
      }
      int g = ct * 2 + (quad >> 1);
      *(bf16x4*)(pT + rowL * 64 + ((g ^ (rowL & 7)) << 3) + (quad & 1) * 4) = pw;
    }
    // PV phase: acc += P @ V^T (K = 64); wave reads only its own 16 P-rows
    __builtin_amdgcn_s_setprio(1);
#pragma unroll
    for (int ks = 0; ks < 2; ks++) {
      bf16x8 pf = *(const bf16x8*)(pT + rowL * 64 + (((ks * 4 + quad) ^ (rowL & 7)) << 3));
#pragma unroll
      for (int dt = 0; dt < 3; dt++) {
        const int vrow = dt * 16 + colL;
        bf16x8 vf = *(const bf16x8*)(vc + vrow * 64 + (((ks * 4 + quad) ^ (vrow & 7)) << 3));
        acc[dt] = __builtin_amdgcn_mfma_f32_16x16x32_bf16(pf, vf, acc[dt], 0, 0, 0);
      }
    }
    __builtin_amdgcn_s_setprio(0);
    // stage next chunk into the other buffer (nobody reads it this iter)
    if (hasNext) write_tile(cur ^ 1);
    __syncthreads();
    cur ^= 1;
  }

  // rowsum reduce: lanes {colL, colL+16, colL+32, colL+48} hold partials of row colL
  rowsum += __shfl_xor(rowsum, 16, 64);
  rowsum += __shfl_xor(rowsum, 32, 64);

  if (MODE == 0) {
#pragma unroll
    for (int dt = 0; dt < 3; dt++)
#pragma unroll
      for (int r = 0; r < 4; r++) {
        int a = r0 + wv * 16 + quad * 4 + r;
        size_t rowD = ((size_t)seg * 64 + bh) * 48 + dt * 16 + colL;
        if (a < AR)
          OutP[rowD * ADV_W + a] = acc[dt][r];
        else if (a < ADV_W)
          OutP[rowD * ADV_W + a] = 0.f;   // identical zero from all segs: benign
      }
    if (quad == 0) {
      int a = r0 + rowL;                   // rowL = wv*16 + colL
      if (a < AR)
        RsP[((size_t)seg * 64 + bh) * ADV_W + a] = rowsum;
    }
  } else {
    float inv[4];
#pragma unroll
    for (int r = 0; r < 4; r++) inv[r] = 1.f / __shfl(rowsum, quad * 4 + r, 64);
#pragma unroll
    for (int dt = 0; dt < 3; dt++)
#pragma unroll
      for (int r = 0; r < 4; r++) {
        int n = r0 + wv * 16 + quad * 4 + r;
        if (n < AR)
          Out[((size_t)bI * AR + n) * DIM + h * HEAD_DIM + dt * 16 + colL] = (bf16)(acc[dt][r] * inv[r]);
      }
  }
}

// ---------------- attn1 partial reduce: advT = sum(advP)/sum(rsP) ---------------
__global__ void attn1_reduce(const float* __restrict__ advP, const float* __restrict__ rsP,
                             bf16* __restrict__ advT) {
  int idx = blockIdx.x * 256 + threadIdx.x;
  if (idx >= 64 * 48 * ADV_W) return;
  int a = idx % ADV_W;
  int d = (idx / ADV_W) % 48;
  int bh = idx / (ADV_W * 48);
  if (a >= ADLA_N) { advT[idx] = (bf16)0.f; return; }
  float s = 0.f, rs = 0.f;
#pragma unroll
  for (int g = 0; g < SEG; g++) {
    s  += advP[(((size_t)g * 64 + bh) * 48 + d) * ADV_W + a];
    rs += rsP[((size_t)g * 64 + bh) * ADV_W + a];
  }
  advT[((size_t)bh * 48 + d) * ADV_W + a] = (bf16)(s / rs);
}

// ---------------- depthwise 3x3x3 conv, z-column register-blocked ---------------
__global__ __launch_bounds__(256)
void dwc_kernel(const bf16* __restrict__ v, const float* __restrict__ w,
                const float* __restrict__ bias, bf16* __restrict__ io) {
  __shared__ float wts[128 * 27];
  const int tid = threadIdx.x;
  const int cg = blockIdx.y;           // channel group of 128
  const int b  = blockIdx.z;
  for (int i = tid; i < 128 * 27; i += 256)
    wts[i] = w[(size_t)cg * 128 * 27 + i];
  __syncthreads();

  const int wv = tid >> 6, lane = tid & 63;
  const int xy = blockIdx.x * 4 + wv;   // 0..195 (wave-uniform)
  const int x = xy / 14, y = xy % 14;
  const int c0 = lane * 2;              // channel pair within group
  const int cglob = cg * 128 + c0;
  const bf16* vb_ = v + (size_t)b * NTOK * DIM + cglob;
  bf16* iob = io + (size_t)b * NTOK * DIM + cglob + (size_t)(x * 196 + y * 14) * DIM;

  float2 acc[14];
#pragma unroll
  for (int z = 0; z < 14; z++) acc[z] = make_float2(0.f, 0.f);

#pragma unroll
  for (int dx = -1; dx <= 1; dx++) {
    int X = x + dx; if ((unsigned)X >= 14u) continue;
#pragma unroll
    for (int dy = -1; dy <= 1; dy++) {
      int Y = y + dy; if ((unsigned)Y >= 14u) continue;
      const bf16* colp = vb_ + (size_t)(X * 196 + Y * 14) * DIM;
      float2 col[14];
#pragma unroll
      for (int z = 0; z < 14; z++) {
        bf16x2 u = *(const bf16x2*)(colp + (size_t)z * DIM);
        col[z] = make_float2((float)u[0], (float)u[1]);
      }
      const int tb = (dx + 1) * 9 + (dy + 1) * 3;
      const float w0a = wts[c0 * 27 + tb],     w0b = wts[(c0 + 1) * 27 + tb];
      const float w1a = wts[c0 * 27 + tb + 1], w1b = wts[(c0 + 1) * 27 + tb + 1];
      const float w2a = wts[c0 * 27 + tb + 2], w2b = wts[(c0 + 1) * 27 + tb + 2];
#pragma unroll
      for (int z = 0; z < 14; z++) {
        float2 s = acc[z];
        if (z > 0)  { s.x += col[z - 1].x * w0a; s.y += col[z - 1].y * w0b; }
        s.x += col[z].x * w1a; s.y += col[z].y * w1b;
        if (z < 13) { s.x += col[z + 1].x * w2a; s.y += col[z + 1].y * w2b; }
        acc[z] = s;
      }
    }
  }

  const float bsa = bias[cglob], bsb = bias[cglob + 1];
#pragma unroll
  for (int z = 0; z < 14; z++) {
    bf16x2 u = *(const bf16x2*)(iob + (size_t)z * DIM);
    bf16x2 o;
    o[0] = (bf16)((float)u[0] + acc[z].x + bsa);
    o[1] = (bf16)((float)u[1] + acc[z].y + bsb);
    *(bf16x2*)(iob + (size_t)z * DIM) = o;
  }
}

// -------------------------------------------------------------------------------
extern "C" void kernel_launch(void* const* d_in, const int* in_sizes, int n_in,
                              void* d_out, int out_size, void* d_ws, size_t ws_size,
                              hipStream_t stream) {
  const float* x     = (const float*)d_in[0];
  const float* Wq    = (const float*)d_in[1];
  const float* Wkv   = (const float*)d_in[2];
  const float* Wproj = (const float*)d_in[3];
  const float* bproj = (const float*)d_in[4];
  const float* dwcw  = (const float*)d_in[5];
  const float* dwcb  = (const float*)d_in[6];
  const float* an    = (const float*)d_in[7];
  const float* na    = (const float*)d_in[8];
  const float* ahb   = (const float*)d_in[9];
  const float* awb   = (const float*)d_in[10];
  const float* adb   = (const float*)d_in[11];
  const float* hab   = (const float*)d_in[12];
  const float* wab   = (const float*)d_in[13];
  const float* dab   = (const float*)d_in[14];
  float* out = (float*)d_out;

  uint8_t* ws = (uint8_t*)d_ws;
  size_t off = 0;
  auto carveB = [&](size_t bytes) -> void* {
    void* p = ws + off;
    off += ((bytes + 255) & ~(size_t)255);
    return p;
  };
  auto carve = [&](size_t elems) -> bf16* { return (bf16*)carveB(elems * 2); };
  bf16*  wtall  = carve((size_t)1152 * 384);
  bf16*  wprojT = carve((size_t)384 * 384);
  bf16*  qb     = carve((size_t)MTOT * 384 + 128);
  bf16*  kb     = carve((size_t)MTOT * 384 + 128);   // bias2 aliases after attn1
  bf16*  vb     = carve((size_t)MTOT * 384 + 128);   // live until dwc
  bf16*  vTb    = carve((size_t)MTOT * 384 + 128);   // dead after attn1 -> aout aliases
  bf16*  adla   = carve((size_t)BATCH * ADLA_N * 384 + 128);
  bf16*  advT   = carve((size_t)64 * 48 * ADV_W + 128);
  bf16*  bias1  = carve((size_t)8 * ADLA_N * B1W);
  float* advP   = (float*)carveB((size_t)SEG * 64 * 48 * ADV_W * 4);
  float* rsP    = (float*)carveB((size_t)SEG * 64 * ADV_W * 4);
  bf16*  bias2  = kb;    // kb dead after attn1
  bf16*  aout   = vTb;   // vTb dead after attn1

  transpose_weights<<<dim3((1152 * 384 + 384 * 384 + 255) / 256), 256, 0, stream>>>(
      Wq, Wkv, Wproj, wtall, wprojT);
  bias1_kernel<<<dim3(8 * ADLA_N), 256, 0, stream>>>(an, ahb, awb, adb, bias1);
  gemm128<0, float, bf16><<<dim3(8 * 22 * 9), 256, 0, stream>>>(
      x, wtall, MTOT, qb, kb, vb, nullptr);
  transpose_v<<<dim3(43, 6, 8), 256, 0, stream>>>(vb, vTb);
  pool_kernel<<<dim3((BATCH * ADLA_N * DIM + 255) / 256), 256, 0, stream>>>(qb, adla);
  attn_kernel<0><<<dim3(6 * 64 * SEG), 256, 0, stream>>>(
      adla, kb, vTb, bias1, nullptr, advP, rsP,
      ADLA_N, NTOK, B1W, (size_t)384 * NTOK, (size_t)48 * NTOK, NTOK);
  attn1_reduce<<<dim3((64 * 48 * ADV_W + 255) / 256), 256, 0, stream>>>(advP, rsP, advT);
  bias2_kernel<<<dim3(43, 6, 8), 256, 0, stream>>>(na, hab, wab, dab, bias2);
  attn_kernel<1><<<dim3(43 * 64), 256, 0, stream>>>(
      qb, adla, advT, bias2, aout, nullptr, nullptr,
      NTOK, ADLA_N, B2W, (size_t)8 * 48 * ADV_W, (size_t)48 * ADV_W, ADV_W);
  dwc_kernel<<<dim3(49, 3, 8), 256, 0, stream>>>(vb, dwcw, dwcb, aout);
  gemm128<1, bf16, float><<<dim3(8 * 22 * 3), 256, 0, stream>>>(
      aout, wprojT, MTOT, out, nullptr, nullptr, bproj);
}

// Round 10
// 409.939 us; speedup vs baseline: 1.0360x; 1.0360x over previous
//
#include <hip/hip_runtime.h>
#include <hip/hip_bf16.h>
#include <cstdint>

typedef __bf16 bf16;
typedef __attribute__((ext_vector_type(8))) __bf16 bf16x8;
typedef __attribute__((ext_vector_type(4))) __bf16 bf16x4;
typedef __attribute__((ext_vector_type(2))) __bf16 bf16x2;
typedef __attribute__((ext_vector_type(4))) float f32x4;

constexpr int DIM = 384;
constexpr int HEAD_DIM = 48;
constexpr int ADLA_N = 343;
constexpr int NTOK = 2744;        // 14^3
constexpr int BATCH = 8;
constexpr int MTOT = BATCH * NTOK; // 21952
constexpr float SCALE = 0.14433756729740643f; // 48^-0.5
constexpr float LOG2E = 1.4426950408889634f;
constexpr float SCALE2 = 0.20823512f;         // SCALE * log2(e); biases pre-scaled
constexpr int B1W = 2816;          // bias1 padded width (44*64)
constexpr int B2W = 384;           // bias2 padded width (6*64)
constexpr int ADV_W = 352;         // adla_v^T padded cols
constexpr int SEG = 6;             // attn1 column-split segments (8x64 chunks each)

// ---------------- weight transpose (f32 in -> bf16 out) -------------------------
__global__ void transpose_weights(const float* __restrict__ Wq,
                                  const float* __restrict__ Wkv,
                                  const float* __restrict__ Wproj,
                                  bf16* __restrict__ WTall,
                                  bf16* __restrict__ WprojT) {
  int idx = blockIdx.x * 256 + threadIdx.x;
  const int total1 = 1152 * 384;
  if (idx < total1) {
    int j = idx / 384, k = idx % 384;
    WTall[idx] = (bf16)((j < 384) ? Wq[k * 384 + j] : Wkv[k * 768 + (j - 384)]);
  } else {
    int i2 = idx - total1;
    if (i2 < 384 * 384) {
      int j = i2 / 384, k = i2 % 384;
      WprojT[i2] = (bf16)Wproj[k * 384 + j];
    }
  }
}

// ---------------- trilinear interp helpers (out 14 from in 7) ------------------
__device__ __forceinline__ void lin_w(int i, int& i0, int& i1, float& w) {
  float f = 0.5f * (float)i - 0.25f;
  f = fminf(fmaxf(f, 0.0f), 6.0f);
  i0 = (int)f;
  w = f - (float)i0;
  i1 = (i0 + 1 < 7) ? i0 + 1 : 6;
}

__device__ __forceinline__ float interp3(const float* __restrict__ p, int x, int y, int z) {
  int x0, x1, y0, y1, z0, z1; float wx, wy, wz;
  lin_w(x, x0, x1, wx); lin_w(y, y0, y1, wy); lin_w(z, z0, z1, wz);
  float c000 = p[x0*49 + y0*7 + z0], c001 = p[x0*49 + y0*7 + z1];
  float c010 = p[x0*49 + y1*7 + z0], c011 = p[x0*49 + y1*7 + z1];
  float c100 = p[x1*49 + y0*7 + z0], c101 = p[x1*49 + y0*7 + z1];
  float c110 = p[x1*49 + y1*7 + z0], c111 = p[x1*49 + y1*7 + z1];
  float c00 = c000 + wz * (c001 - c000), c01 = c010 + wz * (c011 - c010);
  float c10 = c100 + wz * (c101 - c100), c11 = c110 + wz * (c111 - c110);
  float c0 = c00 + wy * (c01 - c00), c1 = c10 + wy * (c11 - c10);
  return c0 + wx * (c1 - c0);
}

// ---------------- bias1[h][a][B1W] = (interp(an)+ah+aw+ad) * log2e --------------
__global__ void bias1_kernel(const float* __restrict__ an, const float* __restrict__ ah,
                             const float* __restrict__ aw, const float* __restrict__ ad,
                             bf16* __restrict__ out) {
  int h = blockIdx.x / ADLA_N, a = blockIdx.x % ADLA_N;
  const float* anp = an + ((size_t)h * ADLA_N + a) * 343;
  const float* ahp = ah + ((size_t)h * ADLA_N + a) * 14;
  const float* awp = aw + ((size_t)h * ADLA_N + a) * 14;
  const float* adp = ad + ((size_t)h * ADLA_N + a) * 14;
  bf16* op = out + ((size_t)h * ADLA_N + a) * B1W;
  for (int n = threadIdx.x; n < B1W; n += 256) {
    if (n < NTOK) {
      int x = n / 196, y = (n / 14) % 14, z = n % 14;
      float v = interp3(anp, x, y, z) + ahp[x] + awp[y] + adp[z];
      op[n] = (bf16)(v * LOG2E);
    } else {
      op[n] = (bf16)0.f;   // finite zero pad (read by attn1, masked)
    }
  }
}

// ---------------- bias2[h][n][B2W] tiled: lanes-along-n gathers, LDS transpose --
// Pre-scaled by log2(e) (see bias1).
__global__ __launch_bounds__(256)
void bias2_kernel(const float* __restrict__ na, const float* __restrict__ ha,
                  const float* __restrict__ wa, const float* __restrict__ da,
                  bf16* __restrict__ out) {
  __shared__ bf16 t[64 * 66];
  const int tid = threadIdx.x;
  const int wv = tid >> 6, lane = tid & 63;
  const int n0 = blockIdx.x * 64, a0 = blockIdx.y * 64;
  const int h = blockIdx.z;
  const int nc = min(n0 + lane, NTOK - 1);
  const int x = nc / 196, y = (nc / 14) % 14, z = nc % 14;
  int x0, x1, y0, y1, z0, z1; float wx, wy, wz;
  lin_w(x, x0, x1, wx); lin_w(y, y0, y1, wy); lin_w(z, z0, z1, wz);
  const int o[8] = { x0*49 + y0*7 + z0, x0*49 + y0*7 + z1,
                     x0*49 + y1*7 + z0, x0*49 + y1*7 + z1,
                     x1*49 + y0*7 + z0, x1*49 + y0*7 + z1,
                     x1*49 + y1*7 + z0, x1*49 + y1*7 + z1 };
  const float wgt[8] = { (1.f-wx)*(1.f-wy)*(1.f-wz), (1.f-wx)*(1.f-wy)*wz,
                         (1.f-wx)*wy*(1.f-wz),       (1.f-wx)*wy*wz,
                         wx*(1.f-wy)*(1.f-wz),       wx*(1.f-wy)*wz,
                         wx*wy*(1.f-wz),             wx*wy*wz };
#pragma unroll
  for (int j = 0; j < 16; j++) {
    const int al = wv * 16 + j;
    const int a = a0 + al;
    float s = 0.f;
    if (a < ADLA_N) {
      const float* p = na + ((size_t)h * ADLA_N + a) * 343;
#pragma unroll
      for (int k = 0; k < 8; k++) s += p[o[k]] * wgt[k];
      s += ha[((size_t)h * 14 + x) * ADLA_N + a]
         + wa[((size_t)h * 14 + y) * ADLA_N + a]
         + da[((size_t)h * 14 + z) * ADLA_N + a];
    }
    t[lane * 66 + al] = (bf16)(s * LOG2E);
  }
  __syncthreads();
#pragma unroll
  for (int j = 0; j < 16; j++) {
    const int nr = wv * 16 + j;
    if (n0 + nr < NTOK)
      out[((size_t)h * NTOK + n0 + nr) * B2W + a0 + lane] = t[nr * 66 + lane];
  }
}

// ---------------- 128x128 MFMA GEMM, K=384, B^T (bf16) --------------------------
// XCD-panel swizzle (T1) + NEW 1-barrier double-buffered pipeline (the pattern
// proven in attn R6): per K-step, issue next slab's global loads into REGISTERS
// first (latency hides under ds_read+MFMA of the current slab), compute from
// buf[cur], write regs into buf[cur^1], ONE barrier. Old 2-barrier loop had
// ~500cy of naked global latency on the critical path each of the 12 K-steps.
template <int MODE, typename AT, typename OT>
__global__ __launch_bounds__(256)
void gemm128(const AT* __restrict__ A, const bf16* __restrict__ BT, int M,
             OT* __restrict__ O0, bf16* __restrict__ O1, bf16* __restrict__ O2,
             const float* __restrict__ bias) {
  constexpr int NB = (MODE == 0) ? 9 : 3;   // n-panels
  const int id = blockIdx.x;
  const int xcd = id & 7;
  const int t0 = id >> 3;                   // 0 .. 22*NB-1
  const int mi = xcd * 22 + t0 / NB;
  const int ni = t0 % NB;
  if (mi >= 172) return;                    // uniform early-exit (pad blocks)
  const int m0 = mi * 128, n0 = ni * 128;

  __shared__ __align__(16) bf16 As[2][128 * 40];
  __shared__ __align__(16) bf16 Bs[2][128 * 40];
  const int tid = threadIdx.x;
  const int wv = tid >> 6, lane = tid & 63;
  const int wr = wv >> 1, wc = wv & 1;
  f32x4 zero4 = {0.f, 0.f, 0.f, 0.f};
  f32x4 acc[4][4];
#pragma unroll
  for (int i = 0; i < 4; i++)
#pragma unroll
    for (int j = 0; j < 4; j++) acc[i][j] = zero4;

  // prefetch registers: 2 slots each of A,B (slot = row, 8-elem col-group)
  bf16x8 areg[2], breg[2];
  auto load_tile = [&](int k0) {
#pragma unroll
    for (int i = 0; i < 2; i++) {
      int flat = i * 256 + tid;
      int row = flat >> 2, cg = flat & 3;
      int gr = m0 + row; if (gr >= M) gr = M - 1;
      if constexpr (sizeof(AT) == 4) {
        const float4* s4 = (const float4*)(A + (size_t)gr * 384 + k0 + cg * 8);
        float4 a = s4[0], b = s4[1];
        areg[i][0]=(bf16)a.x; areg[i][1]=(bf16)a.y; areg[i][2]=(bf16)a.z; areg[i][3]=(bf16)a.w;
        areg[i][4]=(bf16)b.x; areg[i][5]=(bf16)b.y; areg[i][6]=(bf16)b.z; areg[i][7]=(bf16)b.w;
      } else {
        areg[i] = *(const bf16x8*)(A + (size_t)gr * 384 + k0 + cg * 8);
      }
      int nr = n0 + row;
      breg[i] = *(const bf16x8*)(BT + (size_t)nr * 384 + k0 + cg * 8);
    }
  };
  auto write_tile = [&](int buf) {
#pragma unroll
    for (int i = 0; i < 2; i++) {
      int flat = i * 256 + tid;
      int row = flat >> 2, cg = flat & 3;
      *(bf16x8*)(As[buf] + row * 40 + cg * 8) = areg[i];
      *(bf16x8*)(Bs[buf] + row * 40 + cg * 8) = breg[i];
    }
  };

  load_tile(0);
  write_tile(0);
  __syncthreads();
  int cur = 0;

  for (int k0 = 0; k0 < 384; k0 += 32) {
    const bool hasNext = (k0 + 32 < 384);
    if (hasNext) load_tile(k0 + 32);       // in-flight under this slab's compute

    bf16x8 af[4], bfr[4];
#pragma unroll
    for (int t = 0; t < 4; t++) {
      af[t]  = *(const bf16x8*)(As[cur] + (wr * 64 + t * 16 + (lane & 15)) * 40 + (lane >> 4) * 8);
      bfr[t] = *(const bf16x8*)(Bs[cur] + (wc * 64 + t * 16 + (lane & 15)) * 40 + (lane >> 4) * 8);
    }
    __builtin_amdgcn_s_setprio(1);
#pragma unroll
    for (int rt = 0; rt < 4; rt++)
#pragma unroll
      for (int ct = 0; ct < 4; ct++)
        acc[rt][ct] = __builtin_amdgcn_mfma_f32_16x16x32_bf16(af[rt], bfr[ct], acc[rt][ct], 0, 0, 0);
    __builtin_amdgcn_s_setprio(0);

    if (hasNext) write_tile(cur ^ 1);      // other buffer: no reader conflict
    __syncthreads();
    cur ^= 1;
  }
  const int quad = lane >> 4, colL = lane & 15;
#pragma unroll
  for (int rt = 0; rt < 4; rt++) {
#pragma unroll
    for (int ct = 0; ct < 4; ct++) {
      int gcol = n0 + wc * 64 + ct * 16 + colL;
#pragma unroll
      for (int r = 0; r < 4; r++) {
        int grow = m0 + wr * 64 + rt * 16 + quad * 4 + r;
        if (grow < M) {
          float v = acc[rt][ct][r];
          if (MODE == 1) {
            v += bias[gcol];
            O0[(size_t)grow * 384 + gcol] = (OT)v;   // OT=float for final output
          } else {
            bf16* dst; int c;
            if (gcol < 384)      { dst = (bf16*)O0; c = gcol; }
            else if (gcol < 768) { dst = O1; c = gcol - 384; }
            else                 { dst = O2; c = gcol - 768; }
            dst[(size_t)grow * 384 + c] = (bf16)v;
          }
        }
      }
    }
  }
}

// ---------------- v -> vT  ([b][n][c] -> [b][c][n]) -----------------------------
__global__ void transpose_v(const bf16* __restrict__ v, bf16* __restrict__ vT) {
  __shared__ bf16 t[64][65];
  int n0 = blockIdx.x * 64, c0 = blockIdx.y * 64, b = blockIdx.z;
  int tid = threadIdx.x;
  int cl = tid & 63, rs = tid >> 6;
  for (int j = 0; j < 16; j++) {
    int r = rs * 16 + j;
    int n = n0 + r;
    if (n < NTOK) t[cl][r] = v[((size_t)b * NTOK + n) * DIM + c0 + cl];
  }
  __syncthreads();
  int nl = tid & 63, cs = tid >> 6;
  int n = n0 + nl;
  if (n < NTOK)
    for (int j = 0; j < 16; j++) {
      int cc = cs * 16 + j;
      vT[((size_t)b * DIM + c0 + cc) * NTOK + n] = t[cc][nl];
    }
}

// ---------------- 2x2x2 mean-pool of q -> adla [b][343][384] --------------------
__global__ void pool_kernel(const bf16* __restrict__ q, bf16* __restrict__ adla) {
  int idx = blockIdx.x * 256 + threadIdx.x;
  if (idx >= BATCH * ADLA_N * DIM) return;
  int c = idx % DIM;
  int a = (idx / DIM) % ADLA_N;
  int b = idx / (DIM * ADLA_N);
  int a0 = a / 49, a1 = (a / 7) % 7, a2 = a % 7;
  float s = 0.f;
#pragma unroll
  for (int i = 0; i < 2; i++)
#pragma unroll
    for (int j = 0; j < 2; j++)
#pragma unroll
      for (int k = 0; k < 2; k++) {
        int n = (a0 * 2 + i) * 196 + (a1 * 2 + j) * 14 + (a2 * 2 + k);
        s += (float)q[((size_t)b * NTOK + n) * DIM + c];
      }
  adla[idx] = (bf16)(s * 0.125f);
}

// ---------------- unified no-max streaming attention (bf16 internals) -----------
// S^T-form + reg A-fragments + async-stage split + XCD swizzle + 1-barrier dbuf
// + exp2 softmax + s_setprio around MFMA clusters.
template <int MODE>
__global__ __launch_bounds__(256, 4)
void attn_kernel(const bf16* __restrict__ Amat, const bf16* __restrict__ Kmat,
                 const bf16* __restrict__ Vt, const bf16* __restrict__ Bias,
                 bf16* __restrict__ Out, float* __restrict__ OutP,
                 float* __restrict__ RsP,
                 int AR, int NC, int biasW,
                 size_t vtB, size_t vtH, int vtS) {
  __shared__ __align__(16) bf16 kT[2][64 * 64];
  __shared__ __align__(16) bf16 vTs[2][48 * 64];
  __shared__ __align__(16) bf16 pT[64 * 64];
  const int tid = threadIdx.x;
  const int wv = tid >> 6, lane = tid & 63;

  // ---- XCD-aware swizzled block decomposition (1-D grid) ----
  int h, bI, rblk, seg;
  {
    const int id = blockIdx.x;
    h = id & 7;
    int t = id >> 3;
    if (MODE == 0) { rblk = t % 6; t /= 6; bI = t & 7; seg = t >> 3; }
    else           { bI = t & 7; rblk = t >> 3; seg = 0; }
  }
  const int bh = bI * 8 + h;
  const int r0 = rblk * 64;
  const int quad = lane >> 4, colL = lane & 15;
  const int rowL = wv * 16 + colL;                 // this thread's S-row (fixed)

  // ---- A fragments straight to registers (row clamped; k>=48 zero) ----
  int ar = r0 + rowL; if (ar >= AR) ar = AR - 1;
  const bf16* aRow = Amat + ((size_t)bI * AR + ar) * DIM + h * HEAD_DIM;
  bf16x8 af0 = *(const bf16x8*)(aRow + quad * 8);          // k = quad*8 .. +7 (<48)
  bf16x8 af1;
#pragma unroll
  for (int e = 0; e < 8; e++) af1[e] = (bf16)0.f;
  if (quad < 2) af1 = *(const bf16x8*)(aRow + 32 + quad * 8); // k = 32..47; else 0

  f32x4 zero4 = {0.f, 0.f, 0.f, 0.f};
  f32x4 acc[3] = {zero4, zero4, zero4};
  float rowsum = 0.f;
  const int nCh = (NC + 63) >> 6;                  // 64-col chunks
  const int ch0 = (MODE == 0) ? seg * 8 : 0;
  const int ch1 = (MODE == 0) ? min(nCh, ch0 + 8) : nCh;
  int br = r0 + rowL; if (br >= AR) br = AR - 1;   // clamp (stay inside bias[h])
  const bf16* biasRow = Bias + ((size_t)h * AR + br) * biasW + quad * 4;

  // ---- staging coords (wave-invariant forms) ----
  bf16x8 kreg[2], vreg[2];
  auto load_tile = [&](int ch) {
    const int c0 = ch << 6;
#pragma unroll
    for (int i = 0; i < 2; i++) {
      int flat = i * 256 + tid;
      int row = flat >> 3, cg = flat & 7;
      int kg = (cg < 6) ? cg : 0;                  // cols 48..63 finite dup (A zero there)
      int gr = c0 + row; if (gr >= NC) gr = NC - 1;
      kreg[i] = *(const bf16x8*)(Kmat + ((size_t)bI * NC + gr) * DIM + h * HEAD_DIM + kg * 8);
    }
#pragma unroll
    for (int i = 0; i < 2; i++) {
      int flat = i * 256 + tid;
      int d = flat >> 3; if (d > 47) d = 47;
      int cg = flat & 7;
      int cc = c0 + cg * 8; if (cc > vtS - 8) cc = vtS - 8;  // column clamp
      vreg[i] = *(const bf16x8*)(Vt + (size_t)bI * vtB + (size_t)h * vtH + (size_t)d * vtS + cc);
    }
  };
  auto write_tile = [&](int buf) {
    bf16* kd = kT[buf];
    bf16* vd = vTs[buf];
#pragma unroll
    for (int i = 0; i < 2; i++) {
      int flat = i * 256 + tid;
      int row = flat >> 3, cg = flat & 7;
      *(bf16x8*)(kd + row * 64 + ((cg ^ (row & 7)) << 3)) = kreg[i];
    }
#pragma unroll
    for (int i = 0; i < 2; i++) {
      int flat = i * 256 + tid;
      int d = flat >> 3; if (d > 47) d = 47;
      int cg = flat & 7;
      *(bf16x8*)(vd + d * 64 + ((cg ^ (d & 7)) << 3)) = vreg[i];
    }
  };

  // prologue: stage first chunk into buf0
  load_tile(ch0);
  write_tile(0);
  __syncthreads();
  int cur = 0;

  for (int ch = ch0; ch < ch1; ch++) {
    const int c0 = ch << 6;
    const bool hasNext = (ch + 1 < ch1);
    // issue NEXT chunk's global loads now; they complete under S+exp+PV
    if (hasNext) load_tile(ch + 1);

    // bias vector loads for this chunk (hide under S MFMAs)
    bf16x4 bv[4];
#pragma unroll
    for (int ct = 0; ct < 4; ct++)
      bv[ct] = *(const bf16x4*)(biasRow + c0 + ct * 16);

    const bf16* kc = kT[cur];
    const bf16* vc = vTs[cur];

    // S^T phase: sacc[ct] tile = [c rows ct*16..+16][r cols wv*16..+16]
    f32x4 sacc[4];
#pragma unroll
    for (int ct = 0; ct < 4; ct++) sacc[ct] = zero4;
    __builtin_amdgcn_s_setprio(1);
#pragma unroll
    for (int ct = 0; ct < 4; ct++) {
      int krow = ct * 16 + colL;
      bf16x8 b0 = *(const bf16x8*)(kc + krow * 64 + ((quad ^ (krow & 7)) << 3));
      bf16x8 b1 = *(const bf16x8*)(kc + krow * 64 + (((4 | quad) ^ (krow & 7)) << 3));
      sacc[ct] = __builtin_amdgcn_mfma_f32_16x16x32_bf16(b0, af0, sacc[ct], 0, 0, 0);
      sacc[ct] = __builtin_amdgcn_mfma_f32_16x16x32_bf16(b1, af1, sacc[ct], 0, 0, 0);
    }
    __builtin_amdgcn_s_setprio(0);
    // bias + exp2 -> packed bf16x4 P writes into swizzled pT (own row; no barrier)
#pragma unroll
    for (int ct = 0; ct < 4; ct++) {
      int cbase = c0 + ct * 16 + quad * 4;     // global col of elem 0
      bf16x4 pw;
#pragma unroll
      for (int j = 0; j < 4; j++) {
        float s = fmaf(sacc[ct][j], SCALE2, (float)bv[ct][j]);
        float p = ((cbase + j) < NC) ? __builtin_amdgcn_exp2f(s) : 0.f;
        rowsum += p;
        pw[j] = (bf16)p;
      }
      int g = ct * 2 + (quad >> 1);
      *(bf16x4*)(pT + rowL * 64 + ((g ^ (rowL & 7)) << 3) + (quad & 1) * 4) = pw;
    }
    // PV phase: acc += P @ V^T (K = 64); wave reads only its own 16 P-rows
    __builtin_amdgcn_s_setprio(1);
#pragma unroll
    for (int ks = 0; ks < 2; ks++) {
      bf16x8 pf = *(const bf16x8*)(pT + rowL * 64 + (((ks * 4 + quad) ^ (rowL & 7)) << 3));
#pragma unroll
      for (int dt = 0; dt < 3; dt++) {
        const int vrow = dt * 16 + colL;
        bf16x8 vf = *(const bf16x8*)(vc + vrow * 64 + (((ks * 4 + quad) ^ (vrow & 7)) << 3));
        acc[dt] = __builtin_amdgcn_mfma_f32_16x16x32_bf16(pf, vf, acc[dt], 0, 0, 0);
      }
    }
    __builtin_amdgcn_s_setprio(0);
    // stage next chunk into the other buffer (nobody reads it this iter)
    if (hasNext) write_tile(cur ^ 1);
    __syncthreads();
    cur ^= 1;
  }

  // rowsum reduce: lanes {colL, colL+16, colL+32, colL+48} hold partials of row colL
  rowsum += __shfl_xor(rowsum, 16, 64);
  rowsum += __shfl_xor(rowsum, 32, 64);

  if (MODE == 0) {
#pragma unroll
    for (int dt = 0; dt < 3; dt++)
#pragma unroll
      for (int r = 0; r < 4; r++) {
        int a = r0 + wv * 16 + quad * 4 + r;
        size_t rowD = ((size_t)seg * 64 + bh) * 48 + dt * 16 + colL;
        if (a < AR)
          OutP[rowD * ADV_W + a] = acc[dt][r];
        else if (a < ADV_W)
          OutP[rowD * ADV_W + a] = 0.f;   // identical zero from all segs: benign
      }
    if (quad == 0) {
      int a = r0 + rowL;                   // rowL = wv*16 + colL
      if (a < AR)
        RsP[((size_t)seg * 64 + bh) * ADV_W + a] = rowsum;
    }
  } else {
    float inv[4];
#pragma unroll
    for (int r = 0; r < 4; r++) inv[r] = 1.f / __shfl(rowsum, quad * 4 + r, 64);
#pragma unroll
    for (int dt = 0; dt < 3; dt++)
#pragma unroll
      for (int r = 0; r < 4; r++) {
        int n = r0 + wv * 16 + quad * 4 + r;
        if (n < AR)
          Out[((size_t)bI * AR + n) * DIM + h * HEAD_DIM + dt * 16 + colL] = (bf16)(acc[dt][r] * inv[r]);
      }
  }
}

// ---------------- attn1 partial reduce: advT = sum(advP)/sum(rsP) ---------------
__global__ void attn1_reduce(const float* __restrict__ advP, const float* __restrict__ rsP,
                             bf16* __restrict__ advT) {
  int idx = blockIdx.x * 256 + threadIdx.x;
  if (idx >= 64 * 48 * ADV_W) return;
  int a = idx % ADV_W;
  int d = (idx / ADV_W) % 48;
  int bh = idx / (ADV_W * 48);
  if (a >= ADLA_N) { advT[idx] = (bf16)0.f; return; }
  float s = 0.f, rs = 0.f;
#pragma unroll
  for (int g = 0; g < SEG; g++) {
    s  += advP[(((size_t)g * 64 + bh) * 48 + d) * ADV_W + a];
    rs += rsP[((size_t)g * 64 + bh) * ADV_W + a];
  }
  advT[((size_t)bh * 48 + d) * ADV_W + a] = (bf16)(s / rs);
}

// ---------------- depthwise 3x3x3 conv, z-column register-blocked ---------------
__global__ __launch_bounds__(256)
void dwc_kernel(const bf16* __restrict__ v, const float* __restrict__ w,
                const float* __restrict__ bias, bf16* __restrict__ io) {
  __shared__ float wts[128 * 27];
  const int tid = threadIdx.x;
  const int cg = blockIdx.y;           // channel group of 128
  const int b  = blockIdx.z;
  for (int i = tid; i < 128 * 27; i += 256)
    wts[i] = w[(size_t)cg * 128 * 27 + i];
  __syncthreads();

  const int wv = tid >> 6, lane = tid & 63;
  const int xy = blockIdx.x * 4 + wv;   // 0..195 (wave-uniform)
  const int x = xy / 14, y = xy % 14;
  const int c0 = lane * 2;              // channel pair within group
  const int cglob = cg * 128 + c0;
  const bf16* vb_ = v + (size_t)b * NTOK * DIM + cglob;
  bf16* iob = io + (size_t)b * NTOK * DIM + cglob + (size_t)(x * 196 + y * 14) * DIM;

  float2 acc[14];
#pragma unroll
  for (int z = 0; z < 14; z++) acc[z] = make_float2(0.f, 0.f);

#pragma unroll
  for (int dx = -1; dx <= 1; dx++) {
    int X = x + dx; if ((unsigned)X >= 14u) continue;
#pragma unroll
    for (int dy = -1; dy <= 1; dy++) {
      int Y = y + dy; if ((unsigned)Y >= 14u) continue;
      const bf16* colp = vb_ + (size_t)(X * 196 + Y * 14) * DIM;
      float2 col[14];
#pragma unroll
      for (int z = 0; z < 14; z++) {
        bf16x2 u = *(const bf16x2*)(colp + (size_t)z * DIM);
        col[z] = make_float2((float)u[0], (float)u[1]);
      }
      const int tb = (dx + 1) * 9 + (dy + 1) * 3;
      const float w0a = wts[c0 * 27 + tb],     w0b = wts[(c0 + 1) * 27 + tb];
      const float w1a = wts[c0 * 27 + tb + 1], w1b = wts[(c0 + 1) * 27 + tb + 1];
      const float w2a = wts[c0 * 27 + tb + 2], w2b = wts[(c0 + 1) * 27 + tb + 2];
#pragma unroll
      for (int z = 0; z < 14; z++) {
        float2 s = acc[z];
        if (z > 0)  { s.x += col[z - 1].x * w0a; s.y += col[z - 1].y * w0b; }
        s.x += col[z].x * w1a; s.y += col[z].y * w1b;
        if (z < 13) { s.x += col[z + 1].x * w2a; s.y += col[z + 1].y * w2b; }
        acc[z] = s;
      }
    }
  }

  const float bsa = bias[cglob], bsb = bias[cglob + 1];
#pragma unroll
  for (int z = 0; z < 14; z++) {
    bf16x2 u = *(const bf16x2*)(iob + (size_t)z * DIM);
    bf16x2 o;
    o[0] = (bf16)((float)u[0] + acc[z].x + bsa);
    o[1] = (bf16)((float)u[1] + acc[z].y + bsb);
    *(bf16x2*)(iob + (size_t)z * DIM) = o;
  }
}

// -------------------------------------------------------------------------------
extern "C" void kernel_launch(void* const* d_in, const int* in_sizes, int n_in,
                              void* d_out, int out_size, void* d_ws, size_t ws_size,
                              hipStream_t stream) {
  const float* x     = (const float*)d_in[0];
  const float* Wq    = (const float*)d_in[1];
  const float* Wkv   = (const float*)d_in[2];
  const float* Wproj = (const float*)d_in[3];
  const float* bproj = (const float*)d_in[4];
  const float* dwcw  = (const float*)d_in[5];
  const float* dwcb  = (const float*)d_in[6];
  const float* an    = (const float*)d_in[7];
  const float* na    = (const float*)d_in[8];
  const float* ahb   = (const float*)d_in[9];
  const float* awb   = (const float*)d_in[10];
  const float* adb   = (const float*)d_in[11];
  const float* hab   = (const float*)d_in[12];
  const float* wab   = (const float*)d_in[13];
  const float* dab   = (const float*)d_in[14];
  float* out = (float*)d_out;

  uint8_t* ws = (uint8_t*)d_ws;
  size_t off = 0;
  auto carveB = [&](size_t bytes) -> void* {
    void* p = ws + off;
    off += ((bytes + 255) & ~(size_t)255);
    return p;
  };
  auto carve = [&](size_t elems) -> bf16* { return (bf16*)carveB(elems * 2); };
  bf16*  wtall  = carve((size_t)1152 * 384);
  bf16*  wprojT = carve((size_t)384 * 384);
  bf16*  qb     = carve((size_t)MTOT * 384 + 128);
  bf16*  kb     = carve((size_t)MTOT * 384 + 128);   // bias2 aliases after attn1
  bf16*  vb     = carve((size_t)MTOT * 384 + 128);   // live until dwc
  bf16*  vTb    = carve((size_t)MTOT * 384 + 128);   // dead after attn1 -> aout aliases
  bf16*  adla   = carve((size_t)BATCH * ADLA_N * 384 + 128);
  bf16*  advT   = carve((size_t)64 * 48 * ADV_W + 128);
  bf16*  bias1  = carve((size_t)8 * ADLA_N * B1W);
  float* advP   = (float*)carveB((size_t)SEG * 64 * 48 * ADV_W * 4);
  float* rsP    = (float*)carveB((size_t)SEG * 64 * ADV_W * 4);
  bf16*  bias2  = kb;    // kb dead after attn1
  bf16*  aout   = vTb;   // vTb dead after attn1

  transpose_weights<<<dim3((1152 * 384 + 384 * 384 + 255) / 256), 256, 0, stream>>>(
      Wq, Wkv, Wproj, wtall, wprojT);
  bias1_kernel<<<dim3(8 * ADLA_N), 256, 0, stream>>>(an, ahb, awb, adb, bias1);
  gemm128<0, float, bf16><<<dim3(8 * 22 * 9), 256, 0, stream>>>(
      x, wtall, MTOT, qb, kb, vb, nullptr);
  transpose_v<<<dim3(43, 6, 8), 256, 0, stream>>>(vb, vTb);
  pool_kernel<<<dim3((BATCH * ADLA_N * DIM + 255) / 256), 256, 0, stream>>>(qb, adla);
  attn_kernel<0><<<dim3(6 * 64 * SEG), 256, 0, stream>>>(
      adla, kb, vTb, bias1, nullptr, advP, rsP,
      ADLA_N, NTOK, B1W, (size_t)384 * NTOK, (size_t)48 * NTOK, NTOK);
  attn1_reduce<<<dim3((64 * 48 * ADV_W + 255) / 256), 256, 0, stream>>>(advP, rsP, advT);
  bias2_kernel<<<dim3(43, 6, 8), 256, 0, stream>>>(na, hab, wab, dab, bias2);
  attn_kernel<1><<<dim3(43 * 64), 256, 0, stream>>>(
      qb, adla, advT, bias2, aout, nullptr, nullptr,
      NTOK, ADLA_N, B2W, (size_t)8 * 48 * ADV_W, (size_t)48 * ADV_W, ADV_W);
  dwc_kernel<<<dim3(49, 3, 8), 256, 0, stream>>>(vb, dwcw, dwcb, aout);
  gemm128<1, bf16, float><<<dim3(8 * 22 * 3), 256, 0, stream>>>(
      aout, wprojT, MTOT, out, nullptr, nullptr, bproj);
}